// Round 4
// baseline (171.429 us; speedup 1.0000x reference)
//
#include <hip/hip_runtime.h>

typedef unsigned int uint;
typedef unsigned short ushort;

using bf16x8 = __attribute__((ext_vector_type(8))) short;
using f32x4  = __attribute__((ext_vector_type(4))) float;

// round-to-nearest-even fp32 -> bf16
__device__ __forceinline__ ushort f2b(float f) {
  union { float f; uint i; } v; v.f = f;
  uint r = (v.i + 0x7fffu + ((v.i >> 16) & 1u)) >> 16;
  return (ushort)r;
}
__device__ __forceinline__ bf16x8 ldfrag(const ushort* p) {
  union { uint4 u; bf16x8 v; } x; x.u = *(const uint4*)p; return x.v;
}

// =====================================================================
// Prep: fc1_w [128][54] fp32 -> ws[0..8191]  bf16 [128][64], k>=54 zero
//       out_w [128][128] fp32 -> ws[8192..]  bf16 [128][128]
// Runs every call (ws is re-poisoned by the harness before each launch).
// =====================================================================
__global__ __launch_bounds__(256) void prep_kernel(
    const float* __restrict__ fc1w, const float* __restrict__ outw,
    ushort* __restrict__ ws) {
  const int t = threadIdx.x;
#pragma unroll
  for (int i = 0; i < 32; ++i) {
    const int idx = t * 32 + i;            // 0..8191
    const int row = idx >> 6, k = idx & 63;
    ws[idx] = (k < 54) ? f2b(fc1w[row * 54 + k]) : (ushort)0;
  }
#pragma unroll
  for (int i = 0; i < 64; ++i) {
    const int idx = t * 64 + i;            // 0..16383
    ws[8192 + idx] = f2b(outw[idx]);
  }
}

// =====================================================================
// Fused kernel: 256 threads = 4 waves = 256 samples per block; 512 blocks
// (= 2 blocks/CU, all-resident). Per thread: full conv pipeline in
// registers -> h2 bf16 row in LDS. Then FC in two M=128 halves via
// 16x16x32 bf16 MFMA; B-fragments read directly from L2-resident ws.
// LDS: h2A 36864 + tA 34816 + biases 1024 = 72704 B -> 2 blocks/CU.
// conv (VALU) of one block overlaps FC (MFMA) of the sibling block.
// =====================================================================
__global__ __launch_bounds__(256, 2) void fused_kernel(
    const float* __restrict__ x,
    const float* __restrict__ w1g, const float* __restrict__ b1g,
    const float* __restrict__ w2g, const float* __restrict__ b2g,
    const ushort* __restrict__ wsw,
    const float* __restrict__ fc1b, const float* __restrict__ outb,
    float* __restrict__ out) {
  __shared__ __align__(16) ushort h2A[256][72];   // [s][k] bf16, k<64 data
  __shared__ __align__(16) ushort tA[128][136];   // [s][j] bf16 (per half)
  __shared__ float fb1[128], ob[128];

  const int t = threadIdx.x;
  const int s0 = blockIdx.x * 256;

  if (t < 128) { fb1[t] = fc1b[t]; ob[t] = outb[t]; }

  // ---------------- conv pipeline (per thread = one sample) -------------
  {
    const float* xs = x + (size_t)(s0 + t) * 128;
    float xv[128];
#pragma unroll
    for (int i = 0; i < 32; ++i) {
      const float4 v = ((const float4*)xs)[i];
      xv[4 * i + 0] = v.x; xv[4 * i + 1] = v.y;
      xv[4 * i + 2] = v.z; xv[4 * i + 3] = v.w;
    }

    float w1[3][9], b1[3];
#pragma unroll
    for (int c = 0; c < 3; ++c) {
      b1[c] = b1g[c];
#pragma unroll
      for (int q = 0; q < 9; ++q) w1[c][q] = w1g[c * 9 + q];
    }

    float h1[3][6][6];
#pragma unroll
    for (int pr = 0; pr < 6; ++pr)
#pragma unroll
      for (int pc = 0; pc < 6; ++pc)
#pragma unroll
        for (int ch = 0; ch < 3; ++ch) {
          float m = -3.0e38f;
#pragma unroll
          for (int dr = 0; dr < 2; ++dr)
#pragma unroll
            for (int dc = 0; dc < 2; ++dc) {
              float a = 0.f;
#pragma unroll
              for (int ky = 0; ky < 3; ++ky)
#pragma unroll
                for (int kx = 0; kx < 3; ++kx) {
                  const int r = 2 * pr + dr + ky - 1;
                  const int c = 2 * pc + dc + kx - 1;
                  if (r >= 0 && r < 12 && c >= 0 && c < 12 && (12 * r + c) < 128)
                    a = fmaf(w1[ch][ky * 3 + kx], xv[12 * r + c], a);  // folds
                }
              m = fmaxf(m, a);
            }
          h1[ch][pr][pc] = fmaxf(m + b1[ch], 0.f);
        }

    float h2[54];
#pragma unroll
    for (int o = 0; o < 6; ++o) {
      float w2[27];
#pragma unroll
      for (int q = 0; q < 27; ++q) w2[q] = w2g[o * 27 + q];
      const float bo = b2g[o];
#pragma unroll
      for (int qr = 0; qr < 3; ++qr)
#pragma unroll
        for (int qc = 0; qc < 3; ++qc) {
          float m = -3.0e38f;
#pragma unroll
          for (int dr = 0; dr < 2; ++dr)
#pragma unroll
            for (int dc = 0; dc < 2; ++dc) {
              float a = 0.f;
#pragma unroll
              for (int i = 0; i < 3; ++i)
#pragma unroll
                for (int ky = 0; ky < 3; ++ky)
#pragma unroll
                  for (int kx = 0; kx < 3; ++kx) {
                    const int yy = 2 * qr + dr + ky - 1;
                    const int xx = 2 * qc + dc + kx - 1;
                    if (yy >= 0 && yy < 6 && xx >= 0 && xx < 6)  // folds
                      a = fmaf(w2[i * 9 + ky * 3 + kx], h1[i][yy][xx], a);
                  }
              m = fmaxf(m, a);
            }
          h2[o * 9 + qr * 3 + qc] = fmaxf(m + bo, 0.f);
        }
    }

    // pack to bf16, zero-pad k=54..63, write own LDS row (16B stores)
    uint pk[32];
#pragma unroll
    for (int q = 0; q < 27; ++q)
      pk[q] = (uint)f2b(h2[2 * q]) | ((uint)f2b(h2[2 * q + 1]) << 16);
#pragma unroll
    for (int q = 27; q < 32; ++q) pk[q] = 0u;
#pragma unroll
    for (int i = 0; i < 8; ++i) {
      uint4 v; v.x = pk[4 * i]; v.y = pk[4 * i + 1];
      v.z = pk[4 * i + 2]; v.w = pk[4 * i + 3];
      *(uint4*)&h2A[t][8 * i] = v;
    }
  }
  __syncthreads();

  // ---------------- FC via MFMA, two M=128 halves -----------------------
  const int lane = t & 63, wv = t >> 6;
  const int quad = lane >> 4, lm = lane & 15;
  const ushort* wsA = wsw;          // fc1_w bf16 [128][64]
  const ushort* wsB = wsw + 8192;   // out_w bf16 [128][128]

  for (int h = 0; h < 2; ++h) {
    // phase1: t = relu(h2 @ fc1w^T + b)  M=128 K=64 N=128
    f32x4 acc[2][8];
#pragma unroll
    for (int mt = 0; mt < 2; ++mt)
#pragma unroll
      for (int nt = 0; nt < 8; ++nt) acc[mt][nt] = (f32x4){0.f, 0.f, 0.f, 0.f};

#pragma unroll
    for (int kk = 0; kk < 2; ++kk) {
      const int ko = kk * 32 + quad * 8;
      bf16x8 a[2], b[8];
#pragma unroll
      for (int mt = 0; mt < 2; ++mt)
        a[mt] = ldfrag(&h2A[128 * h + 32 * wv + 16 * mt + lm][ko]);
#pragma unroll
      for (int nt = 0; nt < 8; ++nt)
        b[nt] = ldfrag(wsA + (16 * nt + lm) * 64 + ko);
#pragma unroll
      for (int mt = 0; mt < 2; ++mt)
#pragma unroll
        for (int nt = 0; nt < 8; ++nt)
          acc[mt][nt] = __builtin_amdgcn_mfma_f32_16x16x32_bf16(
              a[mt], b[nt], acc[mt][nt], 0, 0, 0);
    }

    // bias + relu -> bf16 -> tA (C layout: col=lm16, row=quad*4+r)
#pragma unroll
    for (int mt = 0; mt < 2; ++mt)
#pragma unroll
      for (int nt = 0; nt < 8; ++nt) {
        const int col = 16 * nt + lm;
        const float bj = fb1[col];
#pragma unroll
        for (int r = 0; r < 4; ++r) {
          const int row = 32 * wv + 16 * mt + quad * 4 + r;
          tA[row][col] = f2b(fmaxf(acc[mt][nt][r] + bj, 0.f));
        }
      }
    __syncthreads();  // tA published (and prior phase2 reads finished)

    // phase2: out = t @ outw^T + ob  M=128 K=128 N=128
    f32x4 acc2[2][8];
#pragma unroll
    for (int mt = 0; mt < 2; ++mt)
#pragma unroll
      for (int nt = 0; nt < 8; ++nt) acc2[mt][nt] = (f32x4){0.f, 0.f, 0.f, 0.f};

#pragma unroll
    for (int kk = 0; kk < 4; ++kk) {
      const int ko = kk * 32 + quad * 8;
      bf16x8 a[2], b[8];
#pragma unroll
      for (int mt = 0; mt < 2; ++mt)
        a[mt] = ldfrag(&tA[32 * wv + 16 * mt + lm][ko]);
#pragma unroll
      for (int nt = 0; nt < 8; ++nt)
        b[nt] = ldfrag(wsB + (16 * nt + lm) * 128 + ko);
#pragma unroll
      for (int mt = 0; mt < 2; ++mt)
#pragma unroll
        for (int nt = 0; nt < 8; ++nt)
          acc2[mt][nt] = __builtin_amdgcn_mfma_f32_16x16x32_bf16(
              a[mt], b[nt], acc2[mt][nt], 0, 0, 0);
    }

    // epilogue: + out_b, fp32 stores
#pragma unroll
    for (int mt = 0; mt < 2; ++mt)
#pragma unroll
      for (int nt = 0; nt < 8; ++nt) {
        const int col = 16 * nt + lm;
        const float bo = ob[col];
#pragma unroll
        for (int r = 0; r < 4; ++r) {
          const int srow = s0 + 128 * h + 32 * wv + 16 * mt + quad * 4 + r;
          out[(size_t)srow * 128 + col] = acc2[mt][nt][r] + bo;
        }
      }
    __syncthreads();  // tA reads done before next-half overwrite
  }
}

extern "C" void kernel_launch(void* const* d_in, const int* in_sizes, int n_in,
                              void* d_out, int out_size, void* d_ws, size_t ws_size,
                              hipStream_t stream) {
  const float* x    = (const float*)d_in[0];
  const float* w1   = (const float*)d_in[1];
  const float* b1   = (const float*)d_in[2];
  const float* w2   = (const float*)d_in[3];
  const float* b2   = (const float*)d_in[4];
  const float* fc1w = (const float*)d_in[5];
  const float* fc1b = (const float*)d_in[6];
  const float* outw = (const float*)d_in[7];
  const float* outb = (const float*)d_in[8];
  float* outp = (float*)d_out;
  ushort* ws  = (ushort*)d_ws;   // bf16 weights: 48 KB

  const int N = in_sizes[0] / 128;   // 131072

  prep_kernel<<<1, 256, 0, stream>>>(fc1w, outw, ws);
  fused_kernel<<<N / 256, 256, 0, stream>>>(x, w1, b1, w2, b2, ws,
                                            fc1b, outb, outp);
}